// Round 2
// baseline (432.765 us; speedup 1.0000x reference)
//
#include <hip/hip_runtime.h>
#include <math.h>

#define SDIM 256
#define CH 5
// row = SDIM*CH = 1280 floats = 5120 bytes (16B aligned)

__global__ __launch_bounds__(256) void aug_resample_kernel(
    const float* __restrict__ crops,
    const float* __restrict__ off_frac,
    const int*   __restrict__ crop_size,
    const int*   __restrict__ do_crop,
    const int*   __restrict__ flip,
    const int*   __restrict__ rot_k,
    float* __restrict__ out,
    float* __restrict__ sums)
{
    const int y   = blockIdx.x;   // output row (pre-flip/rot)
    const int b   = blockIdx.y;   // batch
    const int tid = threadIdx.x;  // output column (pre-flip/rot)

    __shared__ float row0[SDIM * CH];
    __shared__ float row1[SDIM * CH];
    __shared__ float wsum[4][CH];

    const bool  docrop = do_crop[b] != 0;
    const float size_f = docrop ? (float)crop_size[b] : 256.0f;
    const float scale  = size_f * (1.0f / 256.0f);
    const float span   = 256.0f - size_f + 1.0f;
    const float off0   = docrop ? floorf(off_frac[2 * b + 0] * span) : 0.0f;
    const float off1   = docrop ? floorf(off_frac[2 * b + 1] * span) : 0.0f;

    // ---- row (axis 0) taps: uniform across the block ----
    const float cy  = ((float)y + 0.5f) * scale - 0.5f + off0;
    const float i0f = floorf(cy);
    const int   r0  = min(max((int)i0f, 0), 255);
    const int   r1  = min(max((int)i0f + 1, 0), 255);
    const float fy  = cy - i0f;

    // ---- stage the two needed input rows in LDS (coalesced float4) ----
    const float4* src0 = reinterpret_cast<const float4*>(crops + ((size_t)b * SDIM + r0) * (SDIM * CH));
    const float4* src1 = reinterpret_cast<const float4*>(crops + ((size_t)b * SDIM + r1) * (SDIM * CH));
    float4* d0 = reinterpret_cast<float4*>(row0);
    float4* d1 = reinterpret_cast<float4*>(row1);
    #pragma unroll
    for (int i = tid; i < (SDIM * CH) / 4; i += 256) { d0[i] = src0[i]; d1[i] = src1[i]; }
    __syncthreads();

    // ---- column (axis 1) taps: per-lane ----
    const int   x   = tid;
    const float cx  = ((float)x + 0.5f) * scale - 0.5f + off1;
    const float j0f = floorf(cx);
    const int   c0  = min(max((int)j0f, 0), 255);
    const int   c1  = min(max((int)j0f + 1, 0), 255);
    const float fx  = cx - j0f;

    const float w00 = (1.0f - fy) * (1.0f - fx);
    const float w01 = (1.0f - fy) * fx;
    const float w10 = fy * (1.0f - fx);
    const float w11 = fy * fx;

    float v[CH];
    #pragma unroll
    for (int ch = 0; ch < CH; ++ch) {
        v[ch] = w00 * row0[c0 * CH + ch] + w01 * row0[c1 * CH + ch]
              + w10 * row1[c0 * CH + ch] + w11 * row1[c1 * CH + ch];
    }

    // ---- per-channel block reduction for the spatial mean ----
    const int lane = tid & 63;
    const int wid  = tid >> 6;
    #pragma unroll
    for (int ch = 0; ch < CH; ++ch) {
        float s = v[ch];
        #pragma unroll
        for (int o = 32; o > 0; o >>= 1) s += __shfl_down(s, o, 64);
        if (lane == 0) wsum[wid][ch] = s;
    }
    __syncthreads();
    if (tid == 0) {
        #pragma unroll
        for (int ch = 0; ch < CH; ++ch) {
            float t = wsum[0][ch] + wsum[1][ch] + wsum[2][ch] + wsum[3][ch];
            atomicAdd(&sums[b * CH + ch], t);
        }
    }

    // ---- flip (axis 1) then rot90^k: fold into the write address ----
    const int xf = flip[b] ? (255 - x) : x;
    const int k  = rot_k[b] & 3;
    int oi, oj;
    switch (k) {
        case 0:  oi = y;        oj = xf;       break;
        case 1:  oi = 255 - xf; oj = y;        break;
        case 2:  oi = 255 - y;  oj = 255 - xf; break;
        default: oi = xf;       oj = 255 - y;  break;
    }
    float* op = out + (((size_t)b * SDIM + oi) * SDIM + oj) * CH;
    #pragma unroll
    for (int ch = 0; ch < CH; ++ch) op[ch] = v[ch];
}

__global__ __launch_bounds__(256) void aug_affine_kernel(
    float* __restrict__ out,
    const float* __restrict__ sums,
    const float* __restrict__ bright,
    const float* __restrict__ contrast)
{
    const float GRAY = (float)(0.2989 + 0.5870 + 0.1140);
    const int b   = blockIdx.y;
    const int pix = blockIdx.x * 256 + threadIdx.x;  // 0..65535

    float* p = out + ((size_t)b * (SDIM * SDIM) + pix) * CH;
    #pragma unroll
    for (int ch = 0; ch < CH; ++ch) {
        const float m  = sums[b * CH + ch] * (1.0f / 65536.0f);
        const float br = bright[b * CH + ch];
        const float co = contrast[b * CH + ch];
        p[ch] = ((p[ch] - m) * co + m + br) * GRAY;
    }
}

extern "C" void kernel_launch(void* const* d_in, const int* in_sizes, int n_in,
                              void* d_out, int out_size, void* d_ws, size_t ws_size,
                              hipStream_t stream) {
    const float* crops     = (const float*)d_in[0];
    const float* off_frac  = (const float*)d_in[1];
    const float* bright    = (const float*)d_in[2];
    const float* contrast  = (const float*)d_in[3];
    const int*   crop_size = (const int*)d_in[4];
    const int*   do_crop   = (const int*)d_in[5];
    const int*   flipb     = (const int*)d_in[6];
    const int*   rot_k     = (const int*)d_in[7];

    float* out  = (float*)d_out;
    float* sums = (float*)d_ws;   // 64*5 floats of scratch for per-(b,c) sums

    hipMemsetAsync(sums, 0, 64 * CH * sizeof(float), stream);

    dim3 blk(256);
    dim3 g1(SDIM, 64);
    aug_resample_kernel<<<g1, blk, 0, stream>>>(crops, off_frac, crop_size, do_crop,
                                                flipb, rot_k, out, sums);
    dim3 g2(SDIM * SDIM / 256, 64);
    aug_affine_kernel<<<g2, blk, 0, stream>>>(out, sums, bright, contrast);
}

// Round 3
// 261.008 us; speedup vs baseline: 1.6580x; 1.6580x over previous
//
#include <hip/hip_runtime.h>
#include <math.h>

#define SDIM 256
#define CH 5
#define ROWF (SDIM * CH)          // 1280 floats per image row
#define NPART 8                   // atomic spread for sums
#define GRAYF 0.9999f             // 0.2989+0.5870+0.1140

// ---------------- K1: per-(b,c) sums of the resampled image ----------------
// mean(R) is invariant under flip/rot90, so K1 only needs the crop+resize.
__global__ __launch_bounds__(256) void aug_sums_kernel(
    const float* __restrict__ crops,
    const float* __restrict__ off_frac,
    const int*   __restrict__ crop_size,
    const int*   __restrict__ do_crop,
    float* __restrict__ part)     // [NPART][64][CH]
{
    const int y   = blockIdx.x;
    const int b   = blockIdx.y;
    const int tid = threadIdx.x;

    __shared__ float row0[ROWF];
    __shared__ float row1[ROWF];
    __shared__ float wsum[4][CH];

    const bool  docrop = do_crop[b] != 0;
    const float size_f = docrop ? (float)crop_size[b] : 256.0f;
    const float scale  = size_f * (1.0f / 256.0f);
    const float span   = 256.0f - size_f + 1.0f;
    const float off0   = docrop ? floorf(off_frac[2 * b + 0] * span) : 0.0f;
    const float off1   = docrop ? floorf(off_frac[2 * b + 1] * span) : 0.0f;

    const float cy  = ((float)y + 0.5f) * scale - 0.5f + off0;
    const float i0f = floorf(cy);
    const int   r0  = min(max((int)i0f, 0), 255);
    const int   r1  = min(max((int)i0f + 1, 0), 255);
    const float fy  = cy - i0f;

    const float4* src0 = reinterpret_cast<const float4*>(crops + ((size_t)b * SDIM + r0) * ROWF);
    const float4* src1 = reinterpret_cast<const float4*>(crops + ((size_t)b * SDIM + r1) * ROWF);
    float4* d0 = reinterpret_cast<float4*>(row0);
    float4* d1 = reinterpret_cast<float4*>(row1);
    for (int i = tid; i < ROWF / 4; i += 256) { d0[i] = src0[i]; d1[i] = src1[i]; }
    __syncthreads();

    const float cx  = ((float)tid + 0.5f) * scale - 0.5f + off1;
    const float j0f = floorf(cx);
    const int   c0  = min(max((int)j0f, 0), 255);
    const int   c1  = min(max((int)j0f + 1, 0), 255);
    const float fx  = cx - j0f;

    const float w00 = (1.0f - fy) * (1.0f - fx);
    const float w01 = (1.0f - fy) * fx;
    const float w10 = fy * (1.0f - fx);
    const float w11 = fy * fx;

    const int lane = tid & 63;
    const int wid  = tid >> 6;
    #pragma unroll
    for (int ch = 0; ch < CH; ++ch) {
        float s = w00 * row0[c0 * CH + ch] + w01 * row0[c1 * CH + ch]
                + w10 * row1[c0 * CH + ch] + w11 * row1[c1 * CH + ch];
        #pragma unroll
        for (int o = 32; o > 0; o >>= 1) s += __shfl_down(s, o, 64);
        if (lane == 0) wsum[wid][ch] = s;
    }
    __syncthreads();
    if (tid == 0) {
        float* dst = part + ((size_t)(y & (NPART - 1)) * 64 + b) * CH;
        #pragma unroll
        for (int ch = 0; ch < CH; ++ch)
            atomicAdd(&dst[ch], wsum[0][ch] + wsum[1][ch] + wsum[2][ch] + wsum[3][ch]);
    }
}

// ---------------- K2: gather-based resample+flip+rot+affine, dense writes ----------------
__global__ __launch_bounds__(256) void aug_out_kernel(
    const float* __restrict__ crops,
    const float* __restrict__ off_frac,
    const int*   __restrict__ crop_size,
    const int*   __restrict__ do_crop,
    const int*   __restrict__ flip,
    const int*   __restrict__ rot_k,
    const float* __restrict__ part,
    const float* __restrict__ bright,
    const float* __restrict__ contrast,
    float* __restrict__ out)
{
    const int oi  = blockIdx.x;   // output row
    const int b   = blockIdx.y;
    const int tid = threadIdx.x;

    // carved shared memory: cbuf[16][260] | rbuf aliases cbuf | obuf | params
    __shared__ float smem[16 * 260 + ROWF + 2 * CH];
    float* cbuf = smem;                       // odd-k: 16 float-cols x 260 (pad)
    float* rbA  = smem;                       // even-k: row r0
    float* rbB  = smem + ROWF;                // even-k: row r1
    float* obuf = smem + 16 * 260;            // output row repack
    float* prm  = smem + 16 * 260 + ROWF;     // aa[5], ab[5]

    const bool  docrop = do_crop[b] != 0;
    const float size_f = docrop ? (float)crop_size[b] : 256.0f;
    const float scale  = size_f * (1.0f / 256.0f);
    const float span   = 256.0f - size_f + 1.0f;
    const float off0   = docrop ? floorf(off_frac[2 * b + 0] * span) : 0.0f;
    const float off1   = docrop ? floorf(off_frac[2 * b + 1] * span) : 0.0f;
    const int   k      = rot_k[b] & 3;
    const bool  flp    = flip[b] != 0;

    // per-channel affine: out = v*aa + ab
    if (tid < CH) {
        float s = 0.0f;
        #pragma unroll
        for (int p = 0; p < NPART; ++p) s += part[((size_t)p * 64 + b) * CH + tid];
        const float m  = s * (1.0f / 65536.0f);
        const float co = contrast[b * CH + tid];
        const float br = bright[b * CH + tid];
        prm[tid]      = co * GRAYF;
        prm[CH + tid] = ((1.0f - co) * m + br) * GRAYF;
    }

    float v[CH];

    if ((k & 1) == 0) {
        // ---- even k: source row uniform, source col varies ----
        const int   y   = (k == 0) ? oi : 255 - oi;
        const float cy  = ((float)y + 0.5f) * scale - 0.5f + off0;
        const float i0f = floorf(cy);
        const int   r0  = min(max((int)i0f, 0), 255);
        const int   r1  = min(max((int)i0f + 1, 0), 255);
        const float fy  = cy - i0f;

        const float4* s0 = reinterpret_cast<const float4*>(crops + ((size_t)b * SDIM + r0) * ROWF);
        const float4* s1 = reinterpret_cast<const float4*>(crops + ((size_t)b * SDIM + r1) * ROWF);
        float4* dA = reinterpret_cast<float4*>(rbA);
        float4* dB = reinterpret_cast<float4*>(rbB);
        for (int i = tid; i < ROWF / 4; i += 256) { dA[i] = s0[i]; dB[i] = s1[i]; }
        __syncthreads();

        const int   xf  = (k == 0) ? tid : 255 - tid;
        const int   x   = flp ? 255 - xf : xf;
        const float cx  = ((float)x + 0.5f) * scale - 0.5f + off1;
        const float j0f = floorf(cx);
        const int   c0  = min(max((int)j0f, 0), 255);
        const int   c1  = min(max((int)j0f + 1, 0), 255);
        const float fx  = cx - j0f;
        #pragma unroll
        for (int ch = 0; ch < CH; ++ch) {
            const float a = rbA[c0 * CH + ch] + fx * (rbA[c1 * CH + ch] - rbA[c0 * CH + ch]);
            const float d = rbB[c0 * CH + ch] + fx * (rbB[c1 * CH + ch] - rbB[c0 * CH + ch]);
            v[ch] = a + fy * (d - a);
        }
    } else {
        // ---- odd k: source col uniform, source row varies ----
        const int   xf  = (k == 1) ? 255 - oi : oi;
        const int   x   = flp ? 255 - xf : xf;
        const float cx  = ((float)x + 0.5f) * scale - 0.5f + off1;
        const float j0f = floorf(cx);
        const int   c0  = min(max((int)j0f, 0), 255);
        const int   c1  = min(max((int)j0f + 1, 0), 255);
        const float fx  = cx - j0f;

        // stage a 16-float col-window x all 256 rows, transposed in LDS
        const int base4 = min((c0 * CH) & ~3, ROWF - 16);
        const float4* rp = reinterpret_cast<const float4*>(crops + ((size_t)b * SDIM + tid) * ROWF + base4);
        const float4 w0 = rp[0], w1 = rp[1], w2 = rp[2], w3 = rp[3];
        cbuf[ 0 * 260 + tid] = w0.x; cbuf[ 1 * 260 + tid] = w0.y;
        cbuf[ 2 * 260 + tid] = w0.z; cbuf[ 3 * 260 + tid] = w0.w;
        cbuf[ 4 * 260 + tid] = w1.x; cbuf[ 5 * 260 + tid] = w1.y;
        cbuf[ 6 * 260 + tid] = w1.z; cbuf[ 7 * 260 + tid] = w1.w;
        cbuf[ 8 * 260 + tid] = w2.x; cbuf[ 9 * 260 + tid] = w2.y;
        cbuf[10 * 260 + tid] = w2.z; cbuf[11 * 260 + tid] = w2.w;
        cbuf[12 * 260 + tid] = w3.x; cbuf[13 * 260 + tid] = w3.y;
        cbuf[14 * 260 + tid] = w3.z; cbuf[15 * 260 + tid] = w3.w;
        __syncthreads();

        const int offA = c0 * CH - base4;
        const int offB = offA + (c1 - c0) * CH;

        const int   y   = (k == 1) ? tid : 255 - tid;
        const float cy  = ((float)y + 0.5f) * scale - 0.5f + off0;
        const float i0f = floorf(cy);
        const int   r0  = min(max((int)i0f, 0), 255);
        const int   r1  = min(max((int)i0f + 1, 0), 255);
        const float fy  = cy - i0f;
        #pragma unroll
        for (int ch = 0; ch < CH; ++ch) {
            const float p00 = cbuf[(offA + ch) * 260 + r0];
            const float p01 = cbuf[(offB + ch) * 260 + r0];
            const float p10 = cbuf[(offA + ch) * 260 + r1];
            const float p11 = cbuf[(offB + ch) * 260 + r1];
            const float a = p00 + fx * (p01 - p00);
            const float d = p10 + fx * (p11 - p10);
            v[ch] = a + fy * (d - a);
        }
    }

    // affine + repack + dense float4 store
    #pragma unroll
    for (int ch = 0; ch < CH; ++ch) obuf[tid * CH + ch] = v[ch] * prm[ch] + prm[CH + ch];
    __syncthreads();

    const float4* ob4 = reinterpret_cast<const float4*>(obuf);
    float4* orow = reinterpret_cast<float4*>(out + ((size_t)b * SDIM + oi) * ROWF);
    for (int i = tid; i < ROWF / 4; i += 256) orow[i] = ob4[i];
}

extern "C" void kernel_launch(void* const* d_in, const int* in_sizes, int n_in,
                              void* d_out, int out_size, void* d_ws, size_t ws_size,
                              hipStream_t stream) {
    const float* crops     = (const float*)d_in[0];
    const float* off_frac  = (const float*)d_in[1];
    const float* bright    = (const float*)d_in[2];
    const float* contrast  = (const float*)d_in[3];
    const int*   crop_size = (const int*)d_in[4];
    const int*   do_crop   = (const int*)d_in[5];
    const int*   flipb     = (const int*)d_in[6];
    const int*   rot_k     = (const int*)d_in[7];

    float* out  = (float*)d_out;
    float* part = (float*)d_ws;   // [NPART][64][CH]

    hipMemsetAsync(part, 0, NPART * 64 * CH * sizeof(float), stream);

    dim3 blk(256);
    dim3 grd(SDIM, 64);
    aug_sums_kernel<<<grd, blk, 0, stream>>>(crops, off_frac, crop_size, do_crop, part);
    aug_out_kernel<<<grd, blk, 0, stream>>>(crops, off_frac, crop_size, do_crop,
                                            flipb, rot_k, part, bright, contrast, out);
}

// Round 4
// 202.662 us; speedup vs baseline: 2.1354x; 1.2879x over previous
//
#include <hip/hip_runtime.h>
#include <math.h>

#define SDIM 256
#define CH 5
#define ROWF (SDIM * CH)      // 1280 floats per image row
#define NCHUNK 16             // K1 row-chunks per image
#define CHROWS 16             // rows per K1 block
#define GRAYF 0.9999f         // 0.2989+0.5870+0.1140

// ============ K1: per-(b,ch) sum of resampled image, separable form ============
// sum(bilinear_resample(A)) = sum_{r,j} A[r,j] * wy[r] * wx[j]; mean is
// invariant under flip/rot90 so those are ignored here.
__global__ __launch_bounds__(256) void aug_sums_kernel(
    const float* __restrict__ crops,
    const float* __restrict__ off_frac,
    const int*   __restrict__ crop_size,
    const int*   __restrict__ do_crop,
    float* __restrict__ part)     // [NCHUNK][64][CH], written (not accumulated)
{
    const int chunk = blockIdx.x;
    const int b     = blockIdx.y;
    const int tid   = threadIdx.x;

    __shared__ float wyl[SDIM];
    __shared__ float wxl[SDIM];
    __shared__ float psum[4][CH];

    const bool  docrop = do_crop[b] != 0;
    const float size_f = docrop ? (float)crop_size[b] : 256.0f;
    const float scale  = size_f * (1.0f / 256.0f);
    const float span   = 256.0f - size_f + 1.0f;
    const float off0   = docrop ? floorf(off_frac[2 * b + 0] * span) : 0.0f;
    const float off1   = docrop ? floorf(off_frac[2 * b + 1] * span) : 0.0f;

    wyl[tid] = 0.0f;
    wxl[tid] = 0.0f;
    __syncthreads();

    // scatter per-axis resample weights (tid = output coordinate)
    {
        const float cy = ((float)tid + 0.5f) * scale - 0.5f + off0;
        const float fl = floorf(cy);
        const float fy = cy - fl;
        const int r0 = min(max((int)fl, 0), 255);
        const int r1 = min(max((int)fl + 1, 0), 255);
        atomicAdd(&wyl[r0], 1.0f - fy);
        atomicAdd(&wyl[r1], fy);

        const float cx = ((float)tid + 0.5f) * scale - 0.5f + off1;
        const float fl2 = floorf(cx);
        const float fx  = cx - fl2;
        const int c0 = min(max((int)fl2, 0), 255);
        const int c1 = min(max((int)fl2 + 1, 0), 255);
        atomicAdd(&wxl[c0], 1.0f - fx);
        atomicAdd(&wxl[c1], fx);
    }
    __syncthreads();

    float accs[5] = {0.0f, 0.0f, 0.0f, 0.0f, 0.0f};

    const float4* src = reinterpret_cast<const float4*>(
        crops + ((size_t)b * SDIM + (size_t)chunk * CHROWS) * ROWF);
    for (int i = tid; i < CHROWS * 320; i += 256) {
        const int r    = i / 320;          // local row
        const int f4   = i - r * 320;
        const float4 v = src[i];
        const float  wr = wyl[chunk * CHROWS + r];
        const int base = f4 * 4;
        const int phase = base % 5;
        const float t0 = v.x * wxl[(base + 0) / 5] * wr;
        const float t1 = v.y * wxl[(base + 1) / 5] * wr;
        const float t2 = v.z * wxl[(base + 2) / 5] * wr;
        const float t3 = v.w * wxl[(base + 3) / 5] * wr;
        switch (phase) {   // ch = (base+e)%5, all indices compile-time constant
            case 0: accs[0]+=t0; accs[1]+=t1; accs[2]+=t2; accs[3]+=t3; break;
            case 1: accs[1]+=t0; accs[2]+=t1; accs[3]+=t2; accs[4]+=t3; break;
            case 2: accs[2]+=t0; accs[3]+=t1; accs[4]+=t2; accs[0]+=t3; break;
            case 3: accs[3]+=t0; accs[4]+=t1; accs[0]+=t2; accs[1]+=t3; break;
            default:accs[4]+=t0; accs[0]+=t1; accs[1]+=t2; accs[2]+=t3; break;
        }
    }

    const int lane = tid & 63;
    const int wv   = tid >> 6;
    #pragma unroll
    for (int ch = 0; ch < CH; ++ch) {
        float s = accs[ch];
        #pragma unroll
        for (int o = 32; o > 0; o >>= 1) s += __shfl_down(s, o, 64);
        if (lane == 0) psum[wv][ch] = s;
    }
    __syncthreads();
    if (tid == 0) {
        #pragma unroll
        for (int ch = 0; ch < CH; ++ch)
            part[((size_t)chunk * 64 + b) * CH + ch] =
                psum[0][ch] + psum[1][ch] + psum[2][ch] + psum[3][ch];
    }
}

// ============ K2: 4 output rows/block, register stores, fused affine ============
__global__ __launch_bounds__(256) void aug_out_kernel(
    const float* __restrict__ crops,
    const float* __restrict__ off_frac,
    const int*   __restrict__ crop_size,
    const int*   __restrict__ do_crop,
    const int*   __restrict__ flip,
    const int*   __restrict__ rot_k,
    const float* __restrict__ part,
    const float* __restrict__ bright,
    const float* __restrict__ contrast,
    float* __restrict__ out)
{
    const int oi0 = blockIdx.x * 4;   // first output row of this block
    const int b   = blockIdx.y;
    const int tid = threadIdx.x;
    const int rr  = tid >> 6;         // output row within block (wave-uniform)
    const int xg  = tid & 63;         // 4-pixel group within row

    __shared__ __align__(16) float smem[28 * 260];  // union: even 5*1280=6400 | odd 28*260=7280
    __shared__ float prm[2 * CH];

    const bool  docrop = do_crop[b] != 0;
    const float size_f = docrop ? (float)crop_size[b] : 256.0f;
    const float scale  = size_f * (1.0f / 256.0f);
    const float span   = 256.0f - size_f + 1.0f;
    const float off0   = docrop ? floorf(off_frac[2 * b + 0] * span) : 0.0f;
    const float off1   = docrop ? floorf(off_frac[2 * b + 1] * span) : 0.0f;
    const int   k      = rot_k[b] & 3;
    const bool  flp    = flip[b] != 0;

    if (tid < CH) {   // per-channel affine out = v*aa + ab (before the staging sync)
        float s = 0.0f;
        #pragma unroll
        for (int p = 0; p < NCHUNK; ++p) s += part[((size_t)p * 64 + b) * CH + tid];
        const float m  = s * (1.0f / 65536.0f);
        const float co = contrast[b * CH + tid];
        const float br = bright[b * CH + tid];
        prm[tid]      = co * GRAYF;
        prm[CH + tid] = ((1.0f - co) * m + br) * GRAYF;
    }

    float vout[20];

    if ((k & 1) == 0) {
        // ---- even k: src row <- oi (wave-uniform), src col <- oj ----
        const int y_min = (k == 0) ? oi0 : 255 - (oi0 + 3);
        const float cymin = ((float)y_min + 0.5f) * scale - 0.5f + off0;
        const int rbase = (int)floorf(cymin);

        const float4* src4 = reinterpret_cast<const float4*>(crops + (size_t)b * SDIM * ROWF);
        float4* dst4 = reinterpret_cast<float4*>(smem);
        for (int i = tid; i < 5 * 320; i += 256) {
            const int w  = i / 320;
            const int f4 = i - w * 320;
            const int rc = min(max(rbase + w, 0), 255);
            dst4[i] = src4[rc * 320 + f4];
        }
        __syncthreads();

        const int oi = oi0 + rr;
        const int y  = (k == 0) ? oi : 255 - oi;
        const float cy  = ((float)y + 0.5f) * scale - 0.5f + off0;
        const float flr = floorf(cy);
        const float fy  = cy - flr;
        const float* rbA = smem + ((int)flr - rbase) * ROWF;
        const float* rbB = rbA + ROWF;

        #pragma unroll
        for (int p = 0; p < 4; ++p) {
            const int oj = xg * 4 + p;
            const int xf = (k == 0) ? oj : 255 - oj;
            const int x  = flp ? 255 - xf : xf;
            const float cx  = ((float)x + 0.5f) * scale - 0.5f + off1;
            const float fl2 = floorf(cx);
            const float fx  = cx - fl2;
            const int c0 = min(max((int)fl2, 0), 255);
            const int c1 = min(max((int)fl2 + 1, 0), 255);
            #pragma unroll
            for (int ch = 0; ch < CH; ++ch) {
                const float aV = rbA[c0 * CH + ch] + fx * (rbA[c1 * CH + ch] - rbA[c0 * CH + ch]);
                const float dV = rbB[c0 * CH + ch] + fx * (rbB[c1 * CH + ch] - rbB[c0 * CH + ch]);
                vout[p * 5 + ch] = aV + fy * (dV - aV);
            }
        }
    } else {
        // ---- odd k: src col <- oi (wave-uniform), src row <- oj ----
        const int xfA = (k == 1) ? 255 - oi0 : oi0;
        const int xfB = (k == 1) ? 255 - (oi0 + 3) : oi0 + 3;
        const int xA = flp ? 255 - xfA : xfA;
        const int xB = flp ? 255 - xfB : xfB;
        const int xmin = min(xA, xB);
        const float cxmin = ((float)xmin + 0.5f) * scale - 0.5f + off1;
        const int cbase = (int)floorf(cxmin);
        const int basef = cbase * CH;
        const int base4 = basef & ~3;
        const bool fastp = (cbase >= 0) && (cbase + 4 <= 255) && (base4 >= 0) && (base4 + 28 <= ROWF);

        if (fastp) {
            const float4* rp = reinterpret_cast<const float4*>(
                crops + ((size_t)b * SDIM + tid) * ROWF + base4);
            const float4 q0 = rp[0], q1 = rp[1], q2 = rp[2], q3 = rp[3];
            const float4 q4 = rp[4], q5 = rp[5], q6 = rp[6];
            smem[ 0*260+tid]=q0.x; smem[ 1*260+tid]=q0.y; smem[ 2*260+tid]=q0.z; smem[ 3*260+tid]=q0.w;
            smem[ 4*260+tid]=q1.x; smem[ 5*260+tid]=q1.y; smem[ 6*260+tid]=q1.z; smem[ 7*260+tid]=q1.w;
            smem[ 8*260+tid]=q2.x; smem[ 9*260+tid]=q2.y; smem[10*260+tid]=q2.z; smem[11*260+tid]=q2.w;
            smem[12*260+tid]=q3.x; smem[13*260+tid]=q3.y; smem[14*260+tid]=q3.z; smem[15*260+tid]=q3.w;
            smem[16*260+tid]=q4.x; smem[17*260+tid]=q4.y; smem[18*260+tid]=q4.z; smem[19*260+tid]=q4.w;
            smem[20*260+tid]=q5.x; smem[21*260+tid]=q5.y; smem[22*260+tid]=q5.z; smem[23*260+tid]=q5.w;
            smem[24*260+tid]=q6.x; smem[25*260+tid]=q6.y; smem[26*260+tid]=q6.z; smem[27*260+tid]=q6.w;
        } else {
            #pragma unroll
            for (int w = 0; w < 28; ++w) {
                const int f2 = base4 + w + ROWF;       // bias to keep div positive
                const int c2 = f2 / 5;
                const int ch = f2 - c2 * 5;
                const int cc = min(max(c2 - 256, 0), 255);
                smem[w * 260 + tid] = crops[((size_t)b * SDIM + tid) * ROWF + cc * CH + ch];
            }
        }
        __syncthreads();

        const int oi = oi0 + rr;
        const int xf = (k == 1) ? 255 - oi : oi;
        const int x  = flp ? 255 - xf : xf;
        const float cx  = ((float)x + 0.5f) * scale - 0.5f + off1;
        const float fl2 = floorf(cx);
        const float fx  = cx - fl2;
        const int slotA = (int)fl2 * CH - base4;   // pre-clamp slot; content is clamped
        const int slotB = slotA + CH;

        #pragma unroll
        for (int p = 0; p < 4; ++p) {
            const int oj = xg * 4 + p;
            const int y  = (k == 1) ? oj : 255 - oj;
            const float cy  = ((float)y + 0.5f) * scale - 0.5f + off0;
            const float flr = floorf(cy);
            const float fy  = cy - flr;
            const int r0 = min(max((int)flr, 0), 255);
            const int r1 = min(max((int)flr + 1, 0), 255);
            #pragma unroll
            for (int ch = 0; ch < CH; ++ch) {
                const float p00 = smem[(slotA + ch) * 260 + r0];
                const float p01 = smem[(slotB + ch) * 260 + r0];
                const float p10 = smem[(slotA + ch) * 260 + r1];
                const float p11 = smem[(slotB + ch) * 260 + r1];
                const float aV = p00 + fx * (p01 - p00);
                const float dV = p10 + fx * (p11 - p10);
                vout[p * 5 + ch] = aV + fy * (dV - aV);
            }
        }
    }

    // ---- fused affine + dense float4 stores straight from registers ----
    float aa[5], ab[5];
    #pragma unroll
    for (int ch = 0; ch < CH; ++ch) { aa[ch] = prm[ch]; ab[ch] = prm[CH + ch]; }

    float4* orow = reinterpret_cast<float4*>(out + ((size_t)b * SDIM + (oi0 + rr)) * ROWF);
    #pragma unroll
    for (int q = 0; q < 5; ++q) {
        float4 st;
        st.x = vout[q*4+0] * aa[(q*4+0)%5] + ab[(q*4+0)%5];
        st.y = vout[q*4+1] * aa[(q*4+1)%5] + ab[(q*4+1)%5];
        st.z = vout[q*4+2] * aa[(q*4+2)%5] + ab[(q*4+2)%5];
        st.w = vout[q*4+3] * aa[(q*4+3)%5] + ab[(q*4+3)%5];
        orow[xg * 5 + q] = st;
    }
}

extern "C" void kernel_launch(void* const* d_in, const int* in_sizes, int n_in,
                              void* d_out, int out_size, void* d_ws, size_t ws_size,
                              hipStream_t stream) {
    const float* crops     = (const float*)d_in[0];
    const float* off_frac  = (const float*)d_in[1];
    const float* bright    = (const float*)d_in[2];
    const float* contrast  = (const float*)d_in[3];
    const int*   crop_size = (const int*)d_in[4];
    const int*   do_crop   = (const int*)d_in[5];
    const int*   flipb     = (const int*)d_in[6];
    const int*   rot_k     = (const int*)d_in[7];

    float* out  = (float*)d_out;
    float* part = (float*)d_ws;   // [NCHUNK][64][CH], fully written by K1 each call

    dim3 blk(256);
    aug_sums_kernel<<<dim3(NCHUNK, 64), blk, 0, stream>>>(crops, off_frac, crop_size, do_crop, part);
    aug_out_kernel<<<dim3(SDIM / 4, 64), blk, 0, stream>>>(crops, off_frac, crop_size, do_crop,
                                                           flipb, rot_k, part, bright, contrast, out);
}

// Round 5
// 189.774 us; speedup vs baseline: 2.2804x; 1.0679x over previous
//
#include <hip/hip_runtime.h>
#include <math.h>

#define SDIM 256
#define CH 5
#define ROWF (SDIM * CH)      // 1280 floats per image row
#define NCHUNK 16             // K1 row-chunks per image
#define CHROWS 16             // rows per K1 block
#define GRAYF 0.9999f         // 0.2989+0.5870+0.1140

// ============ K1: per-(b,ch) sum of resampled image, separable form ============
// sum(bilinear_resample(A)) = sum_{r,j} A[r,j]*wy[r]*wx[j]; flip/rot90 leave the
// mean invariant. Each thread processes 20-float chunks (4 pixels) so the
// channel mapping is STATIC (no divergent switch, no runtime div/mod).
__global__ __launch_bounds__(256) void aug_sums_kernel(
    const float* __restrict__ crops,
    const float* __restrict__ off_frac,
    const int*   __restrict__ crop_size,
    const int*   __restrict__ do_crop,
    float* __restrict__ part)     // [NCHUNK][64][CH], fully written
{
    const int chunk = blockIdx.x;
    const int b     = blockIdx.y;
    const int tid   = threadIdx.x;

    __shared__ __align__(16) float wyl[SDIM];
    __shared__ __align__(16) float wxl[SDIM];
    __shared__ float psum[4][CH];

    const bool  docrop = do_crop[b] != 0;
    const float size_f = docrop ? (float)crop_size[b] : 256.0f;
    const float scale  = size_f * (1.0f / 256.0f);
    const float span   = 256.0f - size_f + 1.0f;
    const float off0   = docrop ? floorf(off_frac[2 * b + 0] * span) : 0.0f;
    const float off1   = docrop ? floorf(off_frac[2 * b + 1] * span) : 0.0f;

    wyl[tid] = 0.0f;
    wxl[tid] = 0.0f;
    __syncthreads();

    {   // scatter per-axis resample weights (tid = output coordinate)
        const float cy = ((float)tid + 0.5f) * scale - 0.5f + off0;
        const float fl = floorf(cy);
        const float fy = cy - fl;
        const int r0 = min(max((int)fl, 0), 255);
        const int r1 = min(max((int)fl + 1, 0), 255);
        atomicAdd(&wyl[r0], 1.0f - fy);
        atomicAdd(&wyl[r1], fy);

        const float cx = ((float)tid + 0.5f) * scale - 0.5f + off1;
        const float fl2 = floorf(cx);
        const float fx  = cx - fl2;
        const int c0 = min(max((int)fl2, 0), 255);
        const int c1 = min(max((int)fl2 + 1, 0), 255);
        atomicAdd(&wxl[c0], 1.0f - fx);
        atomicAdd(&wxl[c1], fx);
    }
    __syncthreads();

    float acc[5] = {0.0f, 0.0f, 0.0f, 0.0f, 0.0f};
    const float* srcbase = crops + ((size_t)b * SDIM + (size_t)chunk * CHROWS) * ROWF;
    const float4* wx4 = reinterpret_cast<const float4*>(wxl);

    #pragma unroll
    for (int it = 0; it < (CHROWS * 64) / 256; ++it) {
        const int m = it * 256 + tid;
        const int r = m >> 6;         // local row (wave-uniform)
        const int t = m & 63;         // 4-pixel chunk in row
        const float4* p = reinterpret_cast<const float4*>(srcbase + r * ROWF + t * 20);
        const float4 q0 = p[0], q1 = p[1], q2 = p[2], q3 = p[3], q4 = p[4];
        const float wr = wyl[chunk * CHROWS + r];
        const float4 wx = wx4[t];     // wx for pixels 4t..4t+3
        const float w0 = wx.x * wr, w1 = wx.y * wr, w2 = wx.z * wr, w3 = wx.w * wr;
        // float j of chunk: pixel 4t + j/5, channel j%5 — all static:
        acc[0] += q0.x * w0; acc[1] += q0.y * w0; acc[2] += q0.z * w0; acc[3] += q0.w * w0;
        acc[4] += q1.x * w0; acc[0] += q1.y * w1; acc[1] += q1.z * w1; acc[2] += q1.w * w1;
        acc[3] += q2.x * w1; acc[4] += q2.y * w1; acc[0] += q2.z * w2; acc[1] += q2.w * w2;
        acc[2] += q3.x * w2; acc[3] += q3.y * w2; acc[4] += q3.z * w2; acc[0] += q3.w * w3;
        acc[1] += q4.x * w3; acc[2] += q4.y * w3; acc[3] += q4.z * w3; acc[4] += q4.w * w3;
    }

    const int lane = tid & 63;
    const int wv   = tid >> 6;
    #pragma unroll
    for (int ch = 0; ch < CH; ++ch) {
        float s = acc[ch];
        #pragma unroll
        for (int o = 32; o > 0; o >>= 1) s += __shfl_down(s, o, 64);
        if (lane == 0) psum[wv][ch] = s;
    }
    __syncthreads();
    if (tid == 0) {
        #pragma unroll
        for (int ch = 0; ch < CH; ++ch)
            part[((size_t)chunk * 64 + b) * CH + ch] =
                psum[0][ch] + psum[1][ch] + psum[2][ch] + psum[3][ch];
    }
}

// ============ K2: 4 output rows/block; stride-64 pixel map (conflict-free LDS);
//               output repacked through LDS for dense float4 stores ============
__global__ __launch_bounds__(256) void aug_out_kernel(
    const float* __restrict__ crops,
    const float* __restrict__ off_frac,
    const int*   __restrict__ crop_size,
    const int*   __restrict__ do_crop,
    const int*   __restrict__ flip,
    const int*   __restrict__ rot_k,
    const float* __restrict__ part,
    const float* __restrict__ bright,
    const float* __restrict__ contrast,
    float* __restrict__ out)
{
    const int oi0  = blockIdx.x * 4;   // first output row of this block
    const int b    = blockIdx.y;
    const int tid  = threadIdx.x;
    const int rr   = tid >> 6;         // output row within block (wave-uniform)
    const int lane = tid & 63;         // lane owns pixels lane+64p, p=0..3

    // union: even-k stage 5*1280=6400 | odd-k stage 28*260=7280 | obuf 4*1280=5120
    __shared__ __align__(16) float smem[28 * 260];
    __shared__ float prm[2 * CH];

    const bool  docrop = do_crop[b] != 0;
    const float size_f = docrop ? (float)crop_size[b] : 256.0f;
    const float scale  = size_f * (1.0f / 256.0f);
    const float span   = 256.0f - size_f + 1.0f;
    const float off0   = docrop ? floorf(off_frac[2 * b + 0] * span) : 0.0f;
    const float off1   = docrop ? floorf(off_frac[2 * b + 1] * span) : 0.0f;
    const int   k      = rot_k[b] & 3;
    const bool  flp    = flip[b] != 0;

    if (tid < CH) {   // per-channel affine out = v*aa + ab (before first sync)
        float s = 0.0f;
        #pragma unroll
        for (int p = 0; p < NCHUNK; ++p) s += part[((size_t)p * 64 + b) * CH + tid];
        const float m  = s * (1.0f / 65536.0f);
        const float co = contrast[b * CH + tid];
        const float br = bright[b * CH + tid];
        prm[tid]      = co * GRAYF;
        prm[CH + tid] = ((1.0f - co) * m + br) * GRAYF;
    }

    float vout[20];   // vout[p*5+ch] for pixel oj = lane + 64p

    if ((k & 1) == 0) {
        // ---- even k: src row <- oi (wave-uniform), src col <- oj ----
        const int y_min = (k == 0) ? oi0 : 255 - (oi0 + 3);
        const float cymin = ((float)y_min + 0.5f) * scale - 0.5f + off0;
        const int rbase = (int)floorf(cymin);

        const float4* src4 = reinterpret_cast<const float4*>(crops + (size_t)b * SDIM * ROWF);
        float4* dst4 = reinterpret_cast<float4*>(smem);
        for (int i = tid; i < 5 * 320; i += 256) {
            const int w  = i / 320;
            const int f4 = i - w * 320;
            const int rc = min(max(rbase + w, 0), 255);
            dst4[i] = src4[rc * 320 + f4];
        }
        __syncthreads();

        const int oi = oi0 + rr;
        const int y  = (k == 0) ? oi : 255 - oi;
        const float cy  = ((float)y + 0.5f) * scale - 0.5f + off0;
        const float flr = floorf(cy);
        const float fy  = cy - flr;
        const float* rbA = smem + ((int)flr - rbase) * ROWF;
        const float* rbB = rbA + ROWF;

        #pragma unroll
        for (int p = 0; p < 4; ++p) {
            const int oj = lane + 64 * p;
            const int xf = (k == 0) ? oj : 255 - oj;
            const int x  = flp ? 255 - xf : xf;
            const float cx  = ((float)x + 0.5f) * scale - 0.5f + off1;
            const float fl2 = floorf(cx);
            const float fx  = cx - fl2;
            const int c0 = min(max((int)fl2, 0), 255);
            const int c1 = min(max((int)fl2 + 1, 0), 255);
            #pragma unroll
            for (int ch = 0; ch < CH; ++ch) {
                const float aV = rbA[c0 * CH + ch] + fx * (rbA[c1 * CH + ch] - rbA[c0 * CH + ch]);
                const float dV = rbB[c0 * CH + ch] + fx * (rbB[c1 * CH + ch] - rbB[c0 * CH + ch]);
                vout[p * 5 + ch] = aV + fy * (dV - aV);
            }
        }
    } else {
        // ---- odd k: src col <- oi (wave-uniform), src row <- oj ----
        const int xfA = (k == 1) ? 255 - oi0 : oi0;
        const int xfB = (k == 1) ? 255 - (oi0 + 3) : oi0 + 3;
        const int xA = flp ? 255 - xfA : xfA;
        const int xB = flp ? 255 - xfB : xfB;
        const int xmin = min(xA, xB);
        const float cxmin = ((float)xmin + 0.5f) * scale - 0.5f + off1;
        const int cbase = (int)floorf(cxmin);
        const int base4 = (cbase * CH) & ~3;
        const bool fastp = (cbase >= 0) && (cbase + 4 <= 255) && (base4 >= 0) && (base4 + 28 <= ROWF);

        if (fastp) {
            const float4* rp = reinterpret_cast<const float4*>(
                crops + ((size_t)b * SDIM + tid) * ROWF + base4);
            const float4 q0 = rp[0], q1 = rp[1], q2 = rp[2], q3 = rp[3];
            const float4 q4 = rp[4], q5 = rp[5], q6 = rp[6];
            smem[ 0*260+tid]=q0.x; smem[ 1*260+tid]=q0.y; smem[ 2*260+tid]=q0.z; smem[ 3*260+tid]=q0.w;
            smem[ 4*260+tid]=q1.x; smem[ 5*260+tid]=q1.y; smem[ 6*260+tid]=q1.z; smem[ 7*260+tid]=q1.w;
            smem[ 8*260+tid]=q2.x; smem[ 9*260+tid]=q2.y; smem[10*260+tid]=q2.z; smem[11*260+tid]=q2.w;
            smem[12*260+tid]=q3.x; smem[13*260+tid]=q3.y; smem[14*260+tid]=q3.z; smem[15*260+tid]=q3.w;
            smem[16*260+tid]=q4.x; smem[17*260+tid]=q4.y; smem[18*260+tid]=q4.z; smem[19*260+tid]=q4.w;
            smem[20*260+tid]=q5.x; smem[21*260+tid]=q5.y; smem[22*260+tid]=q5.z; smem[23*260+tid]=q5.w;
            smem[24*260+tid]=q6.x; smem[25*260+tid]=q6.y; smem[26*260+tid]=q6.z; smem[27*260+tid]=q6.w;
        } else {
            #pragma unroll
            for (int w = 0; w < 28; ++w) {
                const int f2 = base4 + w + ROWF;       // bias keeps div positive
                const int c2 = f2 / 5;
                const int ch = f2 - c2 * 5;
                const int cc = min(max(c2 - 256, 0), 255);
                smem[w * 260 + tid] = crops[((size_t)b * SDIM + tid) * ROWF + cc * CH + ch];
            }
        }
        __syncthreads();

        const int oi = oi0 + rr;
        const int xf = (k == 1) ? 255 - oi : oi;
        const int x  = flp ? 255 - xf : xf;
        const float cx  = ((float)x + 0.5f) * scale - 0.5f + off1;
        const float fl2 = floorf(cx);
        const float fx  = cx - fl2;
        const int slotA = (int)fl2 * CH - base4;   // pre-clamp slot; content clamped
        const int slotB = slotA + CH;

        #pragma unroll
        for (int p = 0; p < 4; ++p) {
            const int oj = lane + 64 * p;
            const int y  = (k == 1) ? oj : 255 - oj;
            const float cy  = ((float)y + 0.5f) * scale - 0.5f + off0;
            const float flr = floorf(cy);
            const float fy  = cy - flr;
            const int r0 = min(max((int)flr, 0), 255);
            const int r1 = min(max((int)flr + 1, 0), 255);
            #pragma unroll
            for (int ch = 0; ch < CH; ++ch) {
                const float p00 = smem[(slotA + ch) * 260 + r0];
                const float p01 = smem[(slotB + ch) * 260 + r0];
                const float p10 = smem[(slotA + ch) * 260 + r1];
                const float p11 = smem[(slotB + ch) * 260 + r1];
                const float aV = p00 + fx * (p01 - p00);
                const float dV = p10 + fx * (p11 - p10);
                vout[p * 5 + ch] = aV + fy * (dV - aV);
            }
        }
    }

    // ---- fused affine in registers ----
    float aa[5], ab[5];
    #pragma unroll
    for (int ch = 0; ch < CH; ++ch) { aa[ch] = prm[ch]; ab[ch] = prm[CH + ch]; }
    #pragma unroll
    for (int p = 0; p < 4; ++p)
        #pragma unroll
        for (int ch = 0; ch < CH; ++ch)
            vout[p * 5 + ch] = vout[p * 5 + ch] * aa[ch] + ab[ch];

    // ---- repack through LDS (stride-5 writes: conflict-free) + dense stores ----
    __syncthreads();   // staging no longer needed; reuse smem as obuf[4][1280]
    #pragma unroll
    for (int p = 0; p < 4; ++p) {
        const int oj = lane + 64 * p;
        #pragma unroll
        for (int ch = 0; ch < CH; ++ch)
            smem[rr * ROWF + oj * CH + ch] = vout[p * 5 + ch];
    }
    __syncthreads();

    const float4* ob4 = reinterpret_cast<const float4*>(smem);
    float4* dst = reinterpret_cast<float4*>(out + ((size_t)b * SDIM + oi0) * ROWF);
    #pragma unroll
    for (int q = 0; q < 5; ++q) dst[q * 256 + tid] = ob4[q * 256 + tid];
}

extern "C" void kernel_launch(void* const* d_in, const int* in_sizes, int n_in,
                              void* d_out, int out_size, void* d_ws, size_t ws_size,
                              hipStream_t stream) {
    const float* crops     = (const float*)d_in[0];
    const float* off_frac  = (const float*)d_in[1];
    const float* bright    = (const float*)d_in[2];
    const float* contrast  = (const float*)d_in[3];
    const int*   crop_size = (const int*)d_in[4];
    const int*   do_crop   = (const int*)d_in[5];
    const int*   flipb     = (const int*)d_in[6];
    const int*   rot_k     = (const int*)d_in[7];

    float* out  = (float*)d_out;
    float* part = (float*)d_ws;   // [NCHUNK][64][CH], fully written by K1 each call

    dim3 blk(256);
    aug_sums_kernel<<<dim3(NCHUNK, 64), blk, 0, stream>>>(crops, off_frac, crop_size, do_crop, part);
    aug_out_kernel<<<dim3(SDIM / 4, 64), blk, 0, stream>>>(crops, off_frac, crop_size, do_crop,
                                                           flipb, rot_k, part, bright, contrast, out);
}

// Round 6
// 184.320 us; speedup vs baseline: 2.3479x; 1.0296x over previous
//
#include <hip/hip_runtime.h>
#include <math.h>

#define SDIM 256
#define CH 5
#define ROWF (SDIM * CH)      // 1280 floats per image row
#define NCHUNK 32             // K1 row-chunks per image
#define CHROWS 8              // rows per K1 block
#define GRAYF 0.9999f         // 0.2989+0.5870+0.1140

// ============ K1: per-(b,ch) sum of resampled image, separable form ============
// sum(bilinear_resample(A)) = sum_{r,j} A[r,j]*wy[r]*wx[j]; flip/rot90 leave the
// mean invariant. Per thread: TWO 20-float chunks, all 10 float4 loads issued
// before any FMA (explicit MLP).
__global__ __launch_bounds__(256) void aug_sums_kernel(
    const float* __restrict__ crops,
    const float* __restrict__ off_frac,
    const int*   __restrict__ crop_size,
    const int*   __restrict__ do_crop,
    float* __restrict__ part)     // [NCHUNK][64][CH], fully written
{
    const int chunk = blockIdx.x;
    const int b     = blockIdx.y;
    const int tid   = threadIdx.x;

    __shared__ __align__(16) float wyl[SDIM];
    __shared__ __align__(16) float wxl[SDIM];
    __shared__ float psum[4][CH];

    const bool  docrop = do_crop[b] != 0;
    const float size_f = docrop ? (float)crop_size[b] : 256.0f;
    const float scale  = size_f * (1.0f / 256.0f);
    const float span   = 256.0f - size_f + 1.0f;
    const float off0   = docrop ? floorf(off_frac[2 * b + 0] * span) : 0.0f;
    const float off1   = docrop ? floorf(off_frac[2 * b + 1] * span) : 0.0f;

    wyl[tid] = 0.0f;
    wxl[tid] = 0.0f;
    __syncthreads();

    {   // scatter per-axis resample weights (tid = output coordinate)
        const float cy = ((float)tid + 0.5f) * scale - 0.5f + off0;
        const float fl = floorf(cy);
        const float fy = cy - fl;
        const int r0 = min(max((int)fl, 0), 255);
        const int r1 = min(max((int)fl + 1, 0), 255);
        atomicAdd(&wyl[r0], 1.0f - fy);
        atomicAdd(&wyl[r1], fy);

        const float cx = ((float)tid + 0.5f) * scale - 0.5f + off1;
        const float fl2 = floorf(cx);
        const float fx  = cx - fl2;
        const int c0 = min(max((int)fl2, 0), 255);
        const int c1 = min(max((int)fl2 + 1, 0), 255);
        atomicAdd(&wxl[c0], 1.0f - fx);
        atomicAdd(&wxl[c1], fx);
    }
    __syncthreads();

    const float* srcbase = crops + ((size_t)b * SDIM + (size_t)chunk * CHROWS) * ROWF;
    const int rA = tid >> 6;        // item 0 row (wave-uniform)
    const int rB = rA + 4;          // item 1 row
    const int t  = tid & 63;        // 4-pixel chunk in row

    const float4* pA = reinterpret_cast<const float4*>(srcbase + rA * ROWF + t * 20);
    const float4* pB = reinterpret_cast<const float4*>(srcbase + rB * ROWF + t * 20);
    // issue all 10 loads before any use
    const float4 a0 = pA[0], a1 = pA[1], a2 = pA[2], a3 = pA[3], a4 = pA[4];
    const float4 b0 = pB[0], b1 = pB[1], b2 = pB[2], b3 = pB[3], b4 = pB[4];

    const float wrA = wyl[chunk * CHROWS + rA];
    const float wrB = wyl[chunk * CHROWS + rB];
    const float4 wx = reinterpret_cast<const float4*>(wxl)[t];

    float acc[5] = {0.0f, 0.0f, 0.0f, 0.0f, 0.0f};
    {
        const float w0 = wx.x * wrA, w1 = wx.y * wrA, w2 = wx.z * wrA, w3 = wx.w * wrA;
        acc[0] += a0.x * w0; acc[1] += a0.y * w0; acc[2] += a0.z * w0; acc[3] += a0.w * w0;
        acc[4] += a1.x * w0; acc[0] += a1.y * w1; acc[1] += a1.z * w1; acc[2] += a1.w * w1;
        acc[3] += a2.x * w1; acc[4] += a2.y * w1; acc[0] += a2.z * w2; acc[1] += a2.w * w2;
        acc[2] += a3.x * w2; acc[3] += a3.y * w2; acc[4] += a3.z * w2; acc[0] += a3.w * w3;
        acc[1] += a4.x * w3; acc[2] += a4.y * w3; acc[3] += a4.z * w3; acc[4] += a4.w * w3;
    }
    {
        const float w0 = wx.x * wrB, w1 = wx.y * wrB, w2 = wx.z * wrB, w3 = wx.w * wrB;
        acc[0] += b0.x * w0; acc[1] += b0.y * w0; acc[2] += b0.z * w0; acc[3] += b0.w * w0;
        acc[4] += b1.x * w0; acc[0] += b1.y * w1; acc[1] += b1.z * w1; acc[2] += b1.w * w1;
        acc[3] += b2.x * w1; acc[4] += b2.y * w1; acc[0] += b2.z * w2; acc[1] += b2.w * w2;
        acc[2] += b3.x * w2; acc[3] += b3.y * w2; acc[4] += b3.z * w2; acc[0] += b3.w * w3;
        acc[1] += b4.x * w3; acc[2] += b4.y * w3; acc[3] += b4.z * w3; acc[4] += b4.w * w3;
    }

    const int lane = tid & 63;
    const int wv   = tid >> 6;
    #pragma unroll
    for (int ch = 0; ch < CH; ++ch) {
        float s = acc[ch];
        #pragma unroll
        for (int o = 32; o > 0; o >>= 1) s += __shfl_down(s, o, 64);
        if (lane == 0) psum[wv][ch] = s;
    }
    __syncthreads();
    if (tid == 0) {
        #pragma unroll
        for (int ch = 0; ch < CH; ++ch)
            part[((size_t)chunk * 64 + b) * CH + ch] =
                psum[0][ch] + psum[1][ch] + psum[2][ch] + psum[3][ch];
    }
}

// ============ K2: 4 output rows/block; stride-64 pixel map; no-crop fast paths ============
__global__ __launch_bounds__(256) void aug_out_kernel(
    const float* __restrict__ crops,
    const float* __restrict__ off_frac,
    const int*   __restrict__ crop_size,
    const int*   __restrict__ do_crop,
    const int*   __restrict__ flip,
    const int*   __restrict__ rot_k,
    const float* __restrict__ part,
    const float* __restrict__ bright,
    const float* __restrict__ contrast,
    float* __restrict__ out)
{
    const int oi0  = blockIdx.x * 4;   // first output row of this block
    const int b    = blockIdx.y;
    const int tid  = threadIdx.x;
    const int rr   = tid >> 6;         // output row within block (wave-uniform)
    const int lane = tid & 63;         // lane owns pixels lane+64p, p=0..3

    // union: even-k stage 5*1280 | odd-k stage 28*260 | obuf 4*1280
    __shared__ __align__(16) float smem[28 * 260];
    __shared__ float prm[2 * CH];

    const bool  docrop = do_crop[b] != 0;
    const float size_f = docrop ? (float)crop_size[b] : 256.0f;
    const float scale  = size_f * (1.0f / 256.0f);
    const float span   = 256.0f - size_f + 1.0f;
    const float off0   = docrop ? floorf(off_frac[2 * b + 0] * span) : 0.0f;
    const float off1   = docrop ? floorf(off_frac[2 * b + 1] * span) : 0.0f;
    const int   k      = rot_k[b] & 3;
    const bool  flp    = flip[b] != 0;

    if (tid < CH) {   // per-channel affine out = v*aa + ab (before first sync)
        float s = 0.0f;
        #pragma unroll
        for (int p = 0; p < NCHUNK; ++p) s += part[((size_t)p * 64 + b) * CH + tid];
        const float m  = s * (1.0f / 65536.0f);
        const float co = contrast[b * CH + tid];
        const float br = bright[b * CH + tid];
        prm[tid]      = co * GRAYF;
        prm[CH + tid] = ((1.0f - co) * m + br) * GRAYF;
    }

    float vout[20];   // vout[p*5+ch] for pixel oj = lane + 64p

    if ((k & 1) == 0) {
        // ---- even k: src row <- oi (wave-uniform), src col <- oj ----
        const int y_min = (k == 0) ? oi0 : 255 - (oi0 + 3);
        const float cymin = ((float)y_min + 0.5f) * scale - 0.5f + off0;
        const int rbase = (int)floorf(cymin);
        const int nst   = docrop ? 5 : 4;    // staged input rows

        const float4* src4 = reinterpret_cast<const float4*>(crops + (size_t)b * SDIM * ROWF);
        float4* dst4 = reinterpret_cast<float4*>(smem);
        for (int i = tid; i < nst * 320; i += 256) {
            const int w  = i / 320;
            const int f4 = i - w * 320;
            const int rc = min(max(rbase + w, 0), 255);
            dst4[i] = src4[rc * 320 + f4];
        }
        __syncthreads();

        const int oi = oi0 + rr;
        const int y  = (k == 0) ? oi : 255 - oi;

        if (!docrop) {
            // exact permutation: fy=0, fx=0, row y staged at slot y-rbase
            const float* rb = smem + (y - rbase) * ROWF;
            #pragma unroll
            for (int p = 0; p < 4; ++p) {
                const int oj = lane + 64 * p;
                const int xf = (k == 0) ? oj : 255 - oj;
                const int x  = flp ? 255 - xf : xf;
                #pragma unroll
                for (int ch = 0; ch < CH; ++ch) vout[p * 5 + ch] = rb[x * CH + ch];
            }
        } else {
            const float cy  = ((float)y + 0.5f) * scale - 0.5f + off0;
            const float flr = floorf(cy);
            const float fy  = cy - flr;
            const float* rbA = smem + ((int)flr - rbase) * ROWF;
            const float* rbB = rbA + ROWF;
            #pragma unroll
            for (int p = 0; p < 4; ++p) {
                const int oj = lane + 64 * p;
                const int xf = (k == 0) ? oj : 255 - oj;
                const int x  = flp ? 255 - xf : xf;
                const float cx  = ((float)x + 0.5f) * scale - 0.5f + off1;
                const float fl2 = floorf(cx);
                const float fx  = cx - fl2;
                const int c0 = min(max((int)fl2, 0), 255);
                const int c1 = min(max((int)fl2 + 1, 0), 255);
                #pragma unroll
                for (int ch = 0; ch < CH; ++ch) {
                    const float aV = rbA[c0 * CH + ch] + fx * (rbA[c1 * CH + ch] - rbA[c0 * CH + ch]);
                    const float dV = rbB[c0 * CH + ch] + fx * (rbB[c1 * CH + ch] - rbB[c0 * CH + ch]);
                    vout[p * 5 + ch] = aV + fy * (dV - aV);
                }
            }
        }
    } else {
        // ---- odd k: src col <- oi (wave-uniform per wave), src row <- oj ----
        const int xfA = (k == 1) ? 255 - oi0 : oi0;
        const int xfB = (k == 1) ? 255 - (oi0 + 3) : oi0 + 3;
        const int xA = flp ? 255 - xfA : xfA;
        const int xB = flp ? 255 - xfB : xfB;
        const int xmin = min(xA, xB);

        if (!docrop) {
            // exact permutation: stage 24-float col window (6 float4/row)
            const int base4 = min((xmin * CH) & ~3, ROWF - 24);
            const float4* rp = reinterpret_cast<const float4*>(
                crops + ((size_t)b * SDIM + tid) * ROWF + base4);
            const float4 q0 = rp[0], q1 = rp[1], q2 = rp[2];
            const float4 q3 = rp[3], q4 = rp[4], q5 = rp[5];
            smem[ 0*260+tid]=q0.x; smem[ 1*260+tid]=q0.y; smem[ 2*260+tid]=q0.z; smem[ 3*260+tid]=q0.w;
            smem[ 4*260+tid]=q1.x; smem[ 5*260+tid]=q1.y; smem[ 6*260+tid]=q1.z; smem[ 7*260+tid]=q1.w;
            smem[ 8*260+tid]=q2.x; smem[ 9*260+tid]=q2.y; smem[10*260+tid]=q2.z; smem[11*260+tid]=q2.w;
            smem[12*260+tid]=q3.x; smem[13*260+tid]=q3.y; smem[14*260+tid]=q3.z; smem[15*260+tid]=q3.w;
            smem[16*260+tid]=q4.x; smem[17*260+tid]=q4.y; smem[18*260+tid]=q4.z; smem[19*260+tid]=q4.w;
            smem[20*260+tid]=q5.x; smem[21*260+tid]=q5.y; smem[22*260+tid]=q5.z; smem[23*260+tid]=q5.w;
            __syncthreads();

            const int oi = oi0 + rr;
            const int xf = (k == 1) ? 255 - oi : oi;
            const int x  = flp ? 255 - xf : xf;
            const int slotA = x * CH - base4;
            #pragma unroll
            for (int p = 0; p < 4; ++p) {
                const int oj = lane + 64 * p;
                const int y  = (k == 1) ? oj : 255 - oj;
                #pragma unroll
                for (int ch = 0; ch < CH; ++ch)
                    vout[p * 5 + ch] = smem[(slotA + ch) * 260 + y];
            }
        } else {
            const float cxmin = ((float)xmin + 0.5f) * scale - 0.5f + off1;
            const int cbase = (int)floorf(cxmin);
            const int base4 = (cbase * CH) & ~3;
            const bool fastp = (cbase >= 0) && (cbase + 4 <= 255) && (base4 >= 0) && (base4 + 28 <= ROWF);

            if (fastp) {
                const float4* rp = reinterpret_cast<const float4*>(
                    crops + ((size_t)b * SDIM + tid) * ROWF + base4);
                const float4 q0 = rp[0], q1 = rp[1], q2 = rp[2], q3 = rp[3];
                const float4 q4 = rp[4], q5 = rp[5], q6 = rp[6];
                smem[ 0*260+tid]=q0.x; smem[ 1*260+tid]=q0.y; smem[ 2*260+tid]=q0.z; smem[ 3*260+tid]=q0.w;
                smem[ 4*260+tid]=q1.x; smem[ 5*260+tid]=q1.y; smem[ 6*260+tid]=q1.z; smem[ 7*260+tid]=q1.w;
                smem[ 8*260+tid]=q2.x; smem[ 9*260+tid]=q2.y; smem[10*260+tid]=q2.z; smem[11*260+tid]=q2.w;
                smem[12*260+tid]=q3.x; smem[13*260+tid]=q3.y; smem[14*260+tid]=q3.z; smem[15*260+tid]=q3.w;
                smem[16*260+tid]=q4.x; smem[17*260+tid]=q4.y; smem[18*260+tid]=q4.z; smem[19*260+tid]=q4.w;
                smem[20*260+tid]=q5.x; smem[21*260+tid]=q5.y; smem[22*260+tid]=q5.z; smem[23*260+tid]=q5.w;
                smem[24*260+tid]=q6.x; smem[25*260+tid]=q6.y; smem[26*260+tid]=q6.z; smem[27*260+tid]=q6.w;
            } else {
                #pragma unroll
                for (int w = 0; w < 28; ++w) {
                    const int f2 = base4 + w + ROWF;       // bias keeps div positive
                    const int c2 = f2 / 5;
                    const int ch = f2 - c2 * 5;
                    const int cc = min(max(c2 - 256, 0), 255);
                    smem[w * 260 + tid] = crops[((size_t)b * SDIM + tid) * ROWF + cc * CH + ch];
                }
            }
            __syncthreads();

            const int oi = oi0 + rr;
            const int xf = (k == 1) ? 255 - oi : oi;
            const int x  = flp ? 255 - xf : xf;
            const float cx  = ((float)x + 0.5f) * scale - 0.5f + off1;
            const float fl2 = floorf(cx);
            const float fx  = cx - fl2;
            const int slotA = (int)fl2 * CH - base4;   // pre-clamp slot; content clamped
            const int slotB = slotA + CH;

            #pragma unroll
            for (int p = 0; p < 4; ++p) {
                const int oj = lane + 64 * p;
                const int y  = (k == 1) ? oj : 255 - oj;
                const float cy  = ((float)y + 0.5f) * scale - 0.5f + off0;
                const float flr = floorf(cy);
                const float fy  = cy - flr;
                const int r0 = min(max((int)flr, 0), 255);
                const int r1 = min(max((int)flr + 1, 0), 255);
                #pragma unroll
                for (int ch = 0; ch < CH; ++ch) {
                    const float p00 = smem[(slotA + ch) * 260 + r0];
                    const float p01 = smem[(slotB + ch) * 260 + r0];
                    const float p10 = smem[(slotA + ch) * 260 + r1];
                    const float p11 = smem[(slotB + ch) * 260 + r1];
                    const float aV = p00 + fx * (p01 - p00);
                    const float dV = p10 + fx * (p11 - p10);
                    vout[p * 5 + ch] = aV + fy * (dV - aV);
                }
            }
        }
    }

    // ---- fused affine in registers ----
    float aa[5], ab[5];
    #pragma unroll
    for (int ch = 0; ch < CH; ++ch) { aa[ch] = prm[ch]; ab[ch] = prm[CH + ch]; }
    #pragma unroll
    for (int p = 0; p < 4; ++p)
        #pragma unroll
        for (int ch = 0; ch < CH; ++ch)
            vout[p * 5 + ch] = vout[p * 5 + ch] * aa[ch] + ab[ch];

    // ---- repack through LDS (stride-5 writes: conflict-free) + dense stores ----
    __syncthreads();   // staging no longer needed; reuse smem as obuf[4][1280]
    #pragma unroll
    for (int p = 0; p < 4; ++p) {
        const int oj = lane + 64 * p;
        #pragma unroll
        for (int ch = 0; ch < CH; ++ch)
            smem[rr * ROWF + oj * CH + ch] = vout[p * 5 + ch];
    }
    __syncthreads();

    const float4* ob4 = reinterpret_cast<const float4*>(smem);
    float4* dst = reinterpret_cast<float4*>(out + ((size_t)b * SDIM + oi0) * ROWF);
    #pragma unroll
    for (int q = 0; q < 5; ++q) dst[q * 256 + tid] = ob4[q * 256 + tid];
}

extern "C" void kernel_launch(void* const* d_in, const int* in_sizes, int n_in,
                              void* d_out, int out_size, void* d_ws, size_t ws_size,
                              hipStream_t stream) {
    const float* crops     = (const float*)d_in[0];
    const float* off_frac  = (const float*)d_in[1];
    const float* bright    = (const float*)d_in[2];
    const float* contrast  = (const float*)d_in[3];
    const int*   crop_size = (const int*)d_in[4];
    const int*   do_crop   = (const int*)d_in[5];
    const int*   flipb     = (const int*)d_in[6];
    const int*   rot_k     = (const int*)d_in[7];

    float* out  = (float*)d_out;
    float* part = (float*)d_ws;   // [NCHUNK][64][CH], fully written by K1 each call

    dim3 blk(256);
    aug_sums_kernel<<<dim3(NCHUNK, 64), blk, 0, stream>>>(crops, off_frac, crop_size, do_crop, part);
    aug_out_kernel<<<dim3(SDIM / 4, 64), blk, 0, stream>>>(crops, off_frac, crop_size, do_crop,
                                                           flipb, rot_k, part, bright, contrast, out);
}